// Round 9
// baseline (416.591 us; speedup 1.0000x reference)
//
#include <hip/hip_runtime.h>
#include <math.h>

#define BDIM 8
#define MDIM 1024
#define CDIM 768
#define ROWS (BDIM * MDIM)   // 8192

typedef __attribute__((ext_vector_type(8))) short short8;   // 8 bf16
typedef __attribute__((ext_vector_type(8))) unsigned short ushort8;
typedef __attribute__((ext_vector_type(4))) float f32x4;

#define MFMA16(a, b, c) __builtin_amdgcn_mfma_f32_16x16x32_bf16((a), (b), (c), 0, 0, 0)

#define BAR() __builtin_amdgcn_s_barrier()
#define FENCE() asm volatile("" ::: "memory")
#define SCHED_FENCE() __builtin_amdgcn_sched_barrier(0)
#define WAIT_LGKM0() asm volatile("s_waitcnt lgkmcnt(0)" ::: "memory")
#define WAIT_LGKM4() asm volatile("s_waitcnt lgkmcnt(4)" ::: "memory")
#define WAIT_LGKM8() asm volatile("s_waitcnt lgkmcnt(8)" ::: "memory")
#define WAIT_VM8() asm volatile("s_waitcnt vmcnt(8)" ::: "memory")
#define WAIT_VM6() asm volatile("s_waitcnt vmcnt(6)" ::: "memory")
#define WAIT_VM4() asm volatile("s_waitcnt vmcnt(4)" ::: "memory")
#define WAIT_VM2() asm volatile("s_waitcnt vmcnt(2)" ::: "memory")
#define WAIT_VM0() asm volatile("s_waitcnt vmcnt(0)" ::: "memory")

__device__ __forceinline__ unsigned short f2bf(float f) {
  unsigned u = __float_as_uint(f);
  return (unsigned short)((u + 0x7FFFu + ((u >> 16) & 1u)) >> 16);
}

// Inline-asm ds_read_b128 (counted lgkm waits only bind to asm reads).
__device__ __forceinline__ short8 dsr128(unsigned off) {
  short8 r;
  asm volatile("ds_read_b128 %0, %1" : "=v"(r) : "v"(off));
  return r;
}

// ---------------------------------------------------------------------------
// Prologue: input converts + weight transpose-converts + V-slice row copies.
// Flat grid of 10752 blocks x 256 threads:
//   [0,3072): convert layout_x; [3072,6144): convert text_x;
//   [6144,10176): transpose_w (168x24);
//   [10176,10464): Wqkv_vr[r][c] = bf16(Wqkv[r][1536+c])   (768x768)
//   [10464,10752): Wkv_vr[r][c]  = bf16(Wkv[r][768+c])     (768x768)
// ---------------------------------------------------------------------------
__global__ __launch_bounds__(256) void prologue(
    const float* __restrict__ xl, const float* __restrict__ xt,
    unsigned short* __restrict__ dxl, unsigned short* __restrict__ dxt,
    const float* __restrict__ W0, const float* __restrict__ W1,
    const float* __restrict__ W2, const float* __restrict__ W3,
    unsigned short* __restrict__ D0, unsigned short* __restrict__ D1,
    unsigned short* __restrict__ D2, unsigned short* __restrict__ D3,
    unsigned short* __restrict__ VR0, unsigned short* __restrict__ VR1) {
  const int bx = blockIdx.x;
  const int tid = threadIdx.x;
  if (bx < 6144) {
    const float* src = bx < 3072 ? xl : xt;
    unsigned short* dst = bx < 3072 ? dxl : dxt;
    const int i = ((bx < 3072 ? bx : bx - 3072) * 256 + tid) * 8;
    const float4 a = *(const float4*)(src + i);
    const float4 b = *(const float4*)(src + i + 4);
    ushort8 o;
    o[0] = f2bf(a.x); o[1] = f2bf(a.y); o[2] = f2bf(a.z); o[3] = f2bf(a.w);
    o[4] = f2bf(b.x); o[5] = f2bf(b.y); o[6] = f2bf(b.z); o[7] = f2bf(b.w);
    *(ushort8*)(dst + i) = o;
  } else if (bx < 10176) {
    int x = bx - 6144;
    int bxx = x % 168;
    const int k0 = (x / 168) * 32;
    const float* W; unsigned short* D; int N;
    if (bxx < 72)       { W = W0; D = D0; N = 2304; }
    else if (bxx < 96)  { W = W1; D = D1; N = 768;  bxx -= 72; }
    else if (bxx < 144) { W = W2; D = D2; N = 1536; bxx -= 96; }
    else                { W = W3; D = D3; N = 768;  bxx -= 144; }
    __shared__ unsigned short t[32][33];
    const int tx = tid & 31, ty = tid >> 5;
    const int n0 = bxx * 32;
#pragma unroll
    for (int i = 0; i < 4; ++i)
      t[ty + i * 8][tx] = f2bf(W[(size_t)(k0 + ty + i * 8) * N + n0 + tx]);
    __syncthreads();
#pragma unroll
    for (int i = 0; i < 4; ++i)
      D[(size_t)(n0 + ty + i * 8) * CDIM + k0 + tx] = t[tx][ty + i * 8];
  } else {
    const int isQ = bx < 10464;
    const int x = bx - (isQ ? 10176 : 10464);       // [0,288)
    const int i = (x * 256 + tid) * 8;               // < 589824; 768%8==0
    const int row = i / 768, col = i - row * 768;
    const float* src = isQ ? (W0 + (size_t)row * 2304 + 1536 + col)
                           : (W2 + (size_t)row * 1536 + 768 + col);
    unsigned short* dst = (isQ ? VR0 : VR1) + i;
    const float4 a = *(const float4*)(src);
    const float4 b = *(const float4*)(src + 4);
    ushort8 o;
    o[0] = f2bf(a.x); o[1] = f2bf(a.y); o[2] = f2bf(a.z); o[3] = f2bf(a.w);
    o[4] = f2bf(b.x); o[5] = f2bf(b.y); o[6] = f2bf(b.z); o[7] = f2bf(b.w);
    *(ushort8*)(dst) = o;
  }
}

// ---------------------------------------------------------------------------
// Shared staging: J row-groups of 8 rows x 64 cols per wave, XOR-chunked.
// ---------------------------------------------------------------------------
template <int J>
__device__ __forceinline__ void stageJ(
    const unsigned short* __restrict__ g, int ld, int k0,
    unsigned short* lds, int wave, int lane) {
  const int gchunk = (lane & 7) ^ (lane >> 3);
#pragma unroll
  for (int j = 0; j < J; ++j) {
    const int grp = wave * J + j;
    const unsigned short* gp =
        g + (size_t)(grp * 8 + (lane >> 3)) * ld + k0 + gchunk * 8;
    __builtin_amdgcn_global_load_lds(
        (const __attribute__((address_space(1))) unsigned int*)gp,
        (__attribute__((address_space(3))) unsigned int*)(lds + grp * 512),
        16, 0, 0);
  }
}

// ---------------------------------------------------------------------------
// 64x128-tile MFMA engine (4 waves of 32x64, acc[2][4]).
// ---------------------------------------------------------------------------
__device__ __forceinline__ void mfma_loop64h(
    const unsigned short* __restrict__ A, int lda,
    const unsigned short* __restrict__ Bt, int ldb, int K,
    unsigned short* As, unsigned short* Bs, f32x4 acc[2][4],
    int wave, int lane) {
  const int wx = wave & 1, wy = wave >> 1;
  const int quad = lane >> 4, l16 = lane & 15;
  for (int k0 = 0; k0 < K; k0 += 64) {
    stageJ<2>(A, lda, k0, As, wave, lane);
    stageJ<4>(Bt, ldb, k0, Bs, wave, lane);
    __syncthreads();
#pragma unroll
    for (int h = 0; h < 2; ++h) {
      const int slot = ((((h << 2) | quad) ^ (l16 & 7))) * 8;
      short8 afr[2], bfr[4];
#pragma unroll
      for (int mt = 0; mt < 2; ++mt)
        afr[mt] = *(const short8*)&As[(wy * 32 + mt * 16 + l16) * 64 + slot];
#pragma unroll
      for (int nt = 0; nt < 4; ++nt)
        bfr[nt] = *(const short8*)&Bs[(wx * 64 + nt * 16 + l16) * 64 + slot];
#pragma unroll
      for (int mt = 0; mt < 2; ++mt)
#pragma unroll
        for (int nt = 0; nt < 4; ++nt)
          acc[mt][nt] = MFMA16(afr[mt], bfr[nt], acc[mt][nt]);
    }
    __syncthreads();
  }
}

// ---------------------------------------------------------------------------
// wpre: folded projection weights + biases. Flat grid 145.
//   blocks [0,72):   Wvq_t[n][c] = (Wqkv_v @ Wq)^T  (12 m-tiles x 6 c-tiles)
//   blocks [72,144): Wvf_t[d][c] = (Wkv_v @ Wffn)^T
//   block 144: bvq[n] = bqkv_v@Wq + bq;  bvf[n] = bkv_v@Wffn + bffn
// (R8 bug: 36 blocks/matrix covered only 3 of 6 c-tiles -> half of each
// folded weight was unwritten poison -> absmax 4e-2.)
// ---------------------------------------------------------------------------
__global__ __launch_bounds__(256, 4) void wpre(
    const unsigned short* __restrict__ Wq_t, const unsigned short* __restrict__ VR0,
    const unsigned short* __restrict__ Wffn_t, const unsigned short* __restrict__ VR1,
    unsigned short* __restrict__ Wvq_t, unsigned short* __restrict__ Wvf_t,
    const float* __restrict__ Wq, const float* __restrict__ Wffn,
    const float* __restrict__ bqkv, const float* __restrict__ bq,
    const float* __restrict__ bkv, const float* __restrict__ bffn,
    float* __restrict__ bvq, float* __restrict__ bvf) {
  const int blk = blockIdx.x;
  const int tid = threadIdx.x;
  if (blk >= 144) {
#pragma unroll
    for (int rep = 0; rep < 3; ++rep) {
      const int n = tid + rep * 256;
      float s1 = bq[n], s2 = bffn[n];
      for (int c = 0; c < 768; ++c) {
        s1 += bqkv[1536 + c] * Wq[(size_t)c * 768 + n];
        s2 += bkv[768 + c] * Wffn[(size_t)c * 768 + n];
      }
      bvq[n] = s1; bvf[n] = s2;
    }
    return;
  }
  __shared__ __align__(16) unsigned short As[64 * 64];
  __shared__ __align__(16) unsigned short Bs[128 * 64];
  int g = blk;
  const unsigned short *A, *Bt; unsigned short* D;
  if (g < 72) { A = Wq_t; Bt = VR0; D = Wvq_t; }
  else { g -= 72; A = Wffn_t; Bt = VR1; D = Wvf_t; }
  const int m0 = (g % 12) * 64, c0 = (g / 12) * 128;   // 12 x 6 tiles
  const int wave = tid >> 6, lane = tid & 63;
  const int wx = wave & 1, wy = wave >> 1;
  const int quad = lane >> 4, l16 = lane & 15;
  const f32x4 vzero = {0.f, 0.f, 0.f, 0.f};
  f32x4 acc[2][4];
#pragma unroll
  for (int mt = 0; mt < 2; ++mt)
#pragma unroll
    for (int nt = 0; nt < 4; ++nt) acc[mt][nt] = vzero;
  mfma_loop64h(A + (size_t)m0 * CDIM, CDIM, Bt + (size_t)c0 * CDIM, CDIM,
               CDIM, As, Bs, acc, wave, lane);
#pragma unroll
  for (int mt = 0; mt < 2; ++mt)
#pragma unroll
    for (int nt = 0; nt < 4; ++nt) {
      const int col = c0 + wx * 64 + nt * 16 + l16;
#pragma unroll
      for (int rg = 0; rg < 4; ++rg) {
        const int row = m0 + wy * 32 + mt * 16 + quad * 4 + rg;
        D[(size_t)row * 768 + col] = f2bf(acc[mt][nt][rg]);
      }
    }
}

#define MFMA_PHASE(GM, GN, AA, BB)                                          \
  do {                                                                      \
    SCHED_FENCE();                                                          \
    __builtin_amdgcn_s_setprio(1);                                          \
    _Pragma("unroll") for (int mf = 0; mf < 4; ++mf)                        \
    _Pragma("unroll") for (int nf = 0; nf < 2; ++nf)                        \
    _Pragma("unroll") for (int kh = 0; kh < 2; ++kh)                        \
        acc[GM][GN][mf][nf] =                                               \
            MFMA16(AA[mf][kh], BB[nf][kh], acc[GM][GN][mf][nf]);            \
    __builtin_amdgcn_s_setprio(0);                                          \
    SCHED_FENCE();                                                          \
  } while (0)

#define RD_A(dst, base)                                                     \
  do {                                                                      \
    _Pragma("unroll") for (int mf = 0; mf < 4; ++mf) {                      \
      dst[mf][0] = dsr128((base) + aRow[mf] + sl0);                         \
      dst[mf][1] = dsr128((base) + aRow[mf] + sl1);                         \
    }                                                                       \
  } while (0)
#define RD_B(dst, base)                                                     \
  do {                                                                      \
    _Pragma("unroll") for (int nf = 0; nf < 2; ++nf) {                      \
      dst[nf][0] = dsr128((base) + bRow[nf] + sl0);                         \
      dst[nf][1] = dsr128((base) + bRow[nf] + sl1);                         \
    }                                                                       \
  } while (0)

// ---------------------------------------------------------------------------
// 256x256 engine (R7 asm-ds_read pipelined schedule, bench 62 us).
// The LAST 768-slice of each part uses the FOLDED weight (Bvw: Wvq_t/Wvf_t)
// and is written transposed into vTd with ZERO bias (bias folded into the
// pv-stage's bvq/bvf).
// ---------------------------------------------------------------------------
__global__ __launch_bounds__(512, 2) void gemm_qkvkv(
    const unsigned short* __restrict__ A0g, const unsigned short* __restrict__ B0g,
    const float* __restrict__ bias0, unsigned short* __restrict__ Y0,
    unsigned short* __restrict__ vT0, const unsigned short* __restrict__ Bvw0,
    const unsigned short* __restrict__ A1g, const unsigned short* __restrict__ B1g,
    const float* __restrict__ bias1, unsigned short* __restrict__ Y1,
    unsigned short* __restrict__ vT1, const unsigned short* __restrict__ Bvw1) {
  __shared__ __align__(16) unsigned short lds[65536];  // 128 KiB, LDS addr 0
  int lin = blockIdx.x;
  const unsigned short *A, *Bt, *Balt; const float* bias;
  unsigned short *Y, *vTd; int lastSlice, m0, c0;
  if (lin < 288) {            // qkv: 32 m-tiles x 9 c-tiles
    A = A0g; Bt = B0g; Balt = Bvw0; bias = bias0; Y = Y0; vTd = vT0;
    lastSlice = 2;
    const int xcd = lin & 7, j = lin >> 3;          // j in [0,36)
    m0 = (xcd * 4 + (j & 3)) * 256; c0 = (j >> 2) * 256;
  } else {                    // kv: 32 m-tiles x 6 c-tiles
    lin -= 288;
    A = A1g; Bt = B1g; Balt = Bvw1; bias = bias1; Y = Y1; vTd = vT1;
    lastSlice = 1;
    const int xcd = lin & 7, j = lin >> 3;          // j in [0,24)
    m0 = (xcd * 4 + (j & 3)) * 256; c0 = (j >> 2) * 256;
  }
  // Folded-weight slice: swap B source (256-tiles never straddle 768-slices).
  const int sw = lastSlice * 768;
  const unsigned short* Bsel = Bt;
  int c0b = c0;
  if (c0 >= sw) { Bsel = Balt; c0b = c0 - sw; }

  const int tid = threadIdx.x;
  const int wave = tid >> 6, lane = tid & 63;
  const int wy = wave >> 2, wx = wave & 3;          // 2 x 4 waves
  const int quad = lane >> 4, l16 = lane & 15;

  const unsigned short* Ah[2] = {A + (size_t)m0 * CDIM,
                                 A + (size_t)(m0 + 128) * CDIM};
  const unsigned short* Bh[2] = {Bsel + (size_t)c0b * CDIM,
                                 Bsel + (size_t)(c0b + 128) * CDIM};

  const unsigned sl0 = (unsigned)((quad ^ (l16 & 7)) * 16);
  const unsigned sl1 = (unsigned)(((4 | quad) ^ (l16 & 7)) * 16);
  unsigned aRow[4], bRow[2];
#pragma unroll
  for (int mf = 0; mf < 4; ++mf)
    aRow[mf] = (unsigned)((wy * 64 + mf * 16 + l16) * 128);
#pragma unroll
  for (int nf = 0; nf < 2; ++nf)
    bRow[nf] = (unsigned)((wx * 32 + nf * 16 + l16) * 128);

  const f32x4 vzero = {0.f, 0.f, 0.f, 0.f};
  f32x4 acc[2][2][4][2];
#pragma unroll
  for (int gm = 0; gm < 2; ++gm)
#pragma unroll
    for (int gn = 0; gn < 2; ++gn)
#pragma unroll
      for (int mf = 0; mf < 4; ++mf)
#pragma unroll
        for (int nf = 0; nf < 2; ++nf) acc[gm][gn][mf][nf] = vzero;
  short8 afrE[4][2], afrO[4][2], b0r[2][2], b1r[2][2];

  stageJ<2>(Ah[0], CDIM, 0, lds + 0, wave, lane);
  stageJ<2>(Bh[0], CDIM, 0, lds + 16384, wave, lane);
  stageJ<2>(Bh[1], CDIM, 0, lds + 24576, wave, lane);
  stageJ<2>(Ah[1], CDIM, 0, lds + 8192, wave, lane);
  stageJ<2>(Ah[0], CDIM, 64, lds + 32768 + 0, wave, lane);
  stageJ<2>(Bh[0], CDIM, 64, lds + 32768 + 16384, wave, lane);
  stageJ<2>(Bh[1], CDIM, 64, lds + 32768 + 24576, wave, lane);
  WAIT_VM8();
  BAR(); FENCE();
  RD_A(afrE, 0u);        // A0(0) @ buf0
  RD_B(b0r, 32768u);     // B0(0) @ buf0

  for (int t = 0; t < 10; ++t) {
    unsigned short* bufcP = lds + (t & 1) * 32768;
    unsigned short* bufnP = lds + ((t + 1) & 1) * 32768;
    const unsigned bc = (unsigned)((t & 1) * 65536);
    const unsigned bn = (unsigned)(((t + 1) & 1) * 65536);
    // ---- P0 ----
    RD_B(b1r, bc + 49152u);
    stageJ<2>(Ah[1], CDIM, (t + 1) * 64, bufnP + 8192, wave, lane);
    WAIT_VM8(); BAR(); WAIT_LGKM4();
    MFMA_PHASE(0, 0, afrE, b0r);
    // ---- P1 ----
    RD_A(afrO, bc + 16384u);
    stageJ<2>(Ah[0], CDIM, (t + 2) * 64, bufcP + 0, wave, lane);
    WAIT_VM8(); BAR(); WAIT_LGKM8();
    MFMA_PHASE(0, 1, afrE, b1r);
    // ---- P2 ----
    RD_A(afrE, bn + 0u);
    stageJ<2>(Bh[0], CDIM, (t + 2) * 64, bufcP + 16384, wave, lane);
    WAIT_VM8(); BAR(); WAIT_LGKM8();
    MFMA_PHASE(1, 0, afrO, b0r);
    // ---- P3 ----
    RD_B(b0r, bn + 32768u);
    stageJ<2>(Bh[1], CDIM, (t + 2) * 64, bufcP + 24576, wave, lane);
    WAIT_VM8(); BAR();
    MFMA_PHASE(1, 1, afrO, b1r);
  }
  // ---- t = 10 ----
  {
    const unsigned bc = 0u, bn = 65536u;
    unsigned short* bufnP = lds + 32768;
    RD_B(b1r, bc + 49152u);
    stageJ<2>(Ah[1], CDIM, 11 * 64, bufnP + 8192, wave, lane);
    WAIT_VM8(); BAR(); WAIT_LGKM4();
    MFMA_PHASE(0, 0, afrE, b0r);

    RD_A(afrO, bc + 16384u);
    WAIT_VM6(); BAR(); WAIT_LGKM8();
    MFMA_PHASE(0, 1, afrE, b1r);

    RD_A(afrE, bn + 0u);
    WAIT_VM4(); BAR(); WAIT_LGKM8();
    MFMA_PHASE(1, 0, afrO, b0r);

    RD_B(b0r, bn + 32768u);
    WAIT_VM2(); BAR();
    MFMA_PHASE(1, 1, afrO, b1r);
  }
  // ---- t = 11 ----
  {
    const unsigned bc = 65536u;
    RD_B(b1r, bc + 49152u);
    WAIT_VM0(); BAR(); WAIT_LGKM4();
    MFMA_PHASE(0, 0, afrE, b0r);

    RD_A(afrO, bc + 16384u);
    WAIT_LGKM8();
    MFMA_PHASE(0, 1, afrE, b1r);

    WAIT_LGKM0();
    MFMA_PHASE(1, 0, afrO, b0r);
    MFMA_PHASE(1, 1, afrO, b1r);
  }

  // Epilogue: slice-routed writes; last slice transposed (folded weight,
  // bias = 0: it is added post-normalize in the pv stage).
#pragma unroll
  for (int gm = 0; gm < 2; ++gm)
#pragma unroll
    for (int gn = 0; gn < 2; ++gn) {
      const int cb2 = c0 + gn * 128 + wx * 32;
      const int slice = cb2 / 768;
      const int rb = m0 + gm * 128 + wy * 64;
      if (slice == lastSlice) {
#pragma unroll
        for (int mf = 0; mf < 4; ++mf) {
          const int row0 = rb + mf * 16 + quad * 4;
          const int b = row0 >> 10, n0 = row0 & 1023;
#pragma unroll
          for (int nf = 0; nf < 2; ++nf) {
            const int gcol = cb2 + nf * 16 + l16;
            const int d = gcol - slice * 768;
            uint2 o;
            o.x = (unsigned)f2bf(acc[gm][gn][mf][nf][0]) |
                  ((unsigned)f2bf(acc[gm][gn][mf][nf][1]) << 16);
            o.y = (unsigned)f2bf(acc[gm][gn][mf][nf][2]) |
                  ((unsigned)f2bf(acc[gm][gn][mf][nf][3]) << 16);
            *(uint2*)&vTd[((size_t)b * CDIM + d) * MDIM + n0] = o;
          }
        }
      } else {
        const size_t sbase = (size_t)slice * ROWS * 768;
#pragma unroll
        for (int mf = 0; mf < 4; ++mf)
#pragma unroll
          for (int nf = 0; nf < 2; ++nf) {
            const int gcol = cb2 + nf * 16 + l16;
            const int lcol = gcol - slice * 768;
            const float bv = bias[gcol];
#pragma unroll
            for (int rg = 0; rg < 4; ++rg) {
              const int row = rb + mf * 16 + quad * 4 + rg;
              Y[sbase + (size_t)row * 768 + lcol] =
                  f2bf(acc[gm][gn][mf][nf][rg] + bv);
            }
          }
      }
    }
}

// ---------------------------------------------------------------------------
// Batched QK^T with fused exp + row-sum on the 64x128 engine.
// grid (8, 16, BDIM) = 1024 blocks. Row sums as race-free partials per
// (cblock, wx): rsp[((cb*2+wx)*8 + b)*1024 + row].
// ---------------------------------------------------------------------------
__global__ __launch_bounds__(256, 4) void gemm_qk64(
    const unsigned short* __restrict__ Qb, const unsigned short* __restrict__ Kb,
    const float* __restrict__ mask, unsigned short* __restrict__ S, float scale,
    float* __restrict__ rsp) {
  __shared__ __align__(16) unsigned short As[64 * 64];
  __shared__ __align__(16) unsigned short Bs[128 * 64];
  const int c0 = blockIdx.x * 128;
  const int m0 = blockIdx.y * 64;
  const int b = blockIdx.z;
  const int tid = threadIdx.x;
  const int wave = tid >> 6, lane = tid & 63;
  const int wx = wave & 1, wy = wave >> 1;
  const int quad = lane >> 4, l16 = lane & 15;

  const f32x4 vzero = {0.f, 0.f, 0.f, 0.f};
  f32x4 acc[2][4];
#pragma unroll
  for (int mt = 0; mt < 2; ++mt)
#pragma unroll
    for (int nt = 0; nt < 4; ++nt) acc[mt][nt] = vzero;

  mfma_loop64h(Qb + ((size_t)b * MDIM + m0) * CDIM, CDIM,
               Kb + ((size_t)b * MDIM + c0) * CDIM, CDIM, CDIM,
               As, Bs, acc, wave, lane);

  const float* maskb = mask + b * MDIM;
  float mrow[2][4], rsum[2][4];
#pragma unroll
  for (int mt = 0; mt < 2; ++mt)
#pragma unroll
    for (int rg = 0; rg < 4; ++rg) {
      mrow[mt][rg] = maskb[m0 + wy * 32 + mt * 16 + quad * 4 + rg];
      rsum[mt][rg] = 0.f;
    }
  unsigned short* Sb = S + (size_t)b * MDIM * MDIM;
#pragma unroll
  for (int nt = 0; nt < 4; ++nt) {
    const int col = c0 + wx * 64 + nt * 16 + l16;
    const float mcol = maskb[col];
#pragma unroll
    for (int mt = 0; mt < 2; ++mt)
#pragma unroll
      for (int rg = 0; rg < 4; ++rg) {
        const int row = m0 + wy * 32 + mt * 16 + quad * 4 + rg;
        const float e = (mrow[mt][rg] * mcol != 0.f)
                            ? __expf(acc[mt][nt][rg] * scale)
                            : 1e-30f;
        Sb[(size_t)row * MDIM + col] = f2bf(e);
        rsum[mt][rg] += e;
      }
  }
  for (int off = 1; off < 16; off <<= 1) {
#pragma unroll
    for (int mt = 0; mt < 2; ++mt)
#pragma unroll
      for (int rg = 0; rg < 4; ++rg)
        rsum[mt][rg] += __shfl_xor(rsum[mt][rg], off, 64);
  }
  if (l16 == 0) {
    float* rs = rsp + ((((size_t)blockIdx.x * 2 + wx) * 8 + b) << 10) +
                m0 + wy * 32;
#pragma unroll
    for (int mt = 0; mt < 2; ++mt)
#pragma unroll
      for (int rg = 0; rg < 4; ++rg)
        rs[mt * 16 + quad * 4 + rg] = rsum[mt][rg];
  }
}

// ---------------------------------------------------------------------------
// O = normalize(S) @ B + bias  on the 64x128 engine; B is a vT-format
// [b][d][n] operand. Writes bf16 (Ob) or f32 (Of) — exactly one non-null.
// Bias is added AFTER normalization (exact fold: normalized rows sum to 1).
// grid (6, 16, BDIM) = 768 blocks.
// ---------------------------------------------------------------------------
__global__ __launch_bounds__(256, 4) void attn_pv64(
    const unsigned short* __restrict__ P, const unsigned short* __restrict__ vT,
    unsigned short* __restrict__ Ob, float* __restrict__ Of,
    const float* __restrict__ rsp, const float* __restrict__ bias) {
  __shared__ __align__(16) unsigned short As[64 * 64];
  __shared__ __align__(16) unsigned short Bs[128 * 64];
  const int c0 = blockIdx.x * 128;
  const int m0 = blockIdx.y * 64;
  const int b = blockIdx.z;
  const int tid = threadIdx.x;
  const int wave = tid >> 6, lane = tid & 63;
  const int wx = wave & 1, wy = wave >> 1;
  const int quad = lane >> 4, l16 = lane & 15;

  const f32x4 vzero = {0.f, 0.f, 0.f, 0.f};
  f32x4 acc[2][4];
#pragma unroll
  for (int mt = 0; mt < 2; ++mt)
#pragma unroll
    for (int nt = 0; nt < 4; ++nt) acc[mt][nt] = vzero;

  mfma_loop64h(P + ((size_t)b * MDIM + m0) * MDIM, MDIM,
               vT + ((size_t)b * CDIM + c0) * MDIM, MDIM, MDIM,
               As, Bs, acc, wave, lane);

  const float* rsb = rsp + (((size_t)l16 * 8 + b) << 10) + m0 + wy * 32;
  float inv[2][4];
#pragma unroll
  for (int mt = 0; mt < 2; ++mt)
#pragma unroll
    for (int rg = 0; rg < 4; ++rg) {
      float s = rsb[mt * 16 + quad * 4 + rg];
      for (int off = 1; off < 16; off <<= 1) s += __shfl_xor(s, off, 64);
      inv[mt][rg] = 1.f / s;
    }
#pragma unroll
  for (int mt = 0; mt < 2; ++mt)
#pragma unroll
    for (int nt = 0; nt < 4; ++nt) {
      const int col = c0 + wx * 64 + nt * 16 + l16;
      const float bv = bias[col];
#pragma unroll
      for (int rg = 0; rg < 4; ++rg) {
        const int row = m0 + wy * 32 + mt * 16 + quad * 4 + rg;
        const float v = acc[mt][nt][rg] * inv[mt][rg] + bv;
        if (Of) Of[(size_t)(b * MDIM + row) * CDIM + col] = v;
        else Ob[(size_t)(b * MDIM + row) * CDIM + col] = f2bf(v);
      }
    }
}

// ---------------------------------------------------------------------------
extern "C" void kernel_launch(void* const* d_in, const int* in_sizes, int n_in,
                              void* d_out, int out_size, void* d_ws, size_t ws_size,
                              hipStream_t stream) {
  const float* layout_x = (const float*)d_in[0];
  const float* text_x   = (const float*)d_in[1];
  const float* maskp    = (const float*)d_in[2];
  const float* Wqkv     = (const float*)d_in[3];
  const float* bqkv     = (const float*)d_in[4];
  const float* Wq       = (const float*)d_in[5];
  const float* bq       = (const float*)d_in[6];
  const float* Wkv      = (const float*)d_in[7];
  const float* bkv      = (const float*)d_in[8];
  const float* Wffn     = (const float*)d_in[9];
  const float* bffn     = (const float*)d_in[10];
  float* out = (float*)d_out;
  char* ws = (char*)d_ws;

  const float scale = 1.0f / sqrtf((float)CDIM);

  // ---- workspace (bytes), end 117,839,872 ----
  unsigned short* xlb     = (unsigned short*)(ws);              // dead after qkvkv
  unsigned short* xtb     = (unsigned short*)(ws + 12582912);   // -> rsp
  unsigned short* Wqkv_t  = (unsigned short*)(ws + 25165824);
  unsigned short* Wq_t    = (unsigned short*)(ws + 28704768);
  unsigned short* Wkv_t   = (unsigned short*)(ws + 29884416);
  unsigned short* Wffn_t  = (unsigned short*)(ws + 32243712);
  unsigned short* Wvq_t   = (unsigned short*)(ws + 33423360);   // folded V@Wq ^T
  unsigned short* Wvf_t   = (unsigned short*)(ws + 34603008);   // folded cV@Wffn ^T
  unsigned short* Qb      = (unsigned short*)(ws + 35782656);   // cqb alias after qk1
  unsigned short* Kb      = (unsigned short*)(ws + 48365568);   // = Qb + 12,582,912
  unsigned short* VWT     = (unsigned short*)(ws + 60948480);   // (x@Wvq)^T [b][d][n]
  unsigned short* cK      = (unsigned short*)(ws + 73531392);
  unsigned short* cVFT    = (unsigned short*)(ws + 86114304);   // (text@Wvf)^T
  unsigned short* S       = (unsigned short*)(ws + 98697216);   // 16.8 MB
  float*          bvq     = (float*)(ws + 115474432);           // 3 KB
  float*          bvf     = (float*)(ws + 115477504);           // 3 KB
  unsigned short* Wqkv_vr = (unsigned short*)(ws + 115480576);  // 1.18 MB
  unsigned short* Wkv_vr  = (unsigned short*)(ws + 116660224);  // 1.18 MB
  unsigned short* cqb     = Qb;          // Qb dead after qk1
  float* rsp = (float*)xtb;              // xtb dead after qkvkv

  // 1) prologue: converts + weight transposes + V-slice row copies
  prologue<<<10752, 256, 0, stream>>>(layout_x, text_x, xlb, xtb,
                                      Wqkv, Wq, Wkv, Wffn,
                                      Wqkv_t, Wq_t, Wkv_t, Wffn_t,
                                      Wqkv_vr, Wkv_vr);
  // 2) folded projection weights Wvq_t, Wvf_t + biases bvq, bvf
  wpre<<<145, 256, 0, stream>>>(Wq_t, Wqkv_vr, Wffn_t, Wkv_vr, Wvq_t, Wvf_t,
                                Wq, Wffn, bqkv, bq, bkv, bffn, bvq, bvf);
  // 3) combined 256^2: {Q,K -> Qb,Kb; x@Wvq -> VWT^T} + {cK; text@Wvf -> cVFT^T}
  gemm_qkvkv<<<480, 512, 0, stream>>>(xlb, Wqkv_t, bqkv, Qb, VWT, Wvq_t,
                                      xtb, Wkv_t, bkv, cK, cVFT, Wvf_t);
  // 4) S = exp(scale*QK^T) masked; rowsum partials
  gemm_qk64<<<dim3(8, 16, BDIM), 256, 0, stream>>>(Qb, Kb, maskp, S, scale, rsp);
  // 5) cq = normalize(S) @ VW + bvq   (pv + folded Wq projection)
  attn_pv64<<<dim3(6, 16, BDIM), 256, 0, stream>>>(S, VWT, cqb, nullptr, rsp, bvq);
  // 6) S = exp(scale*cq cK^T) masked; rowsum partials
  gemm_qk64<<<dim3(8, 16, BDIM), 256, 0, stream>>>(cqb, cK, maskp, S, scale, rsp);
  // 7) out = normalize(S) @ cVF + bvf   (pv + folded Wffn projection, f32)
  attn_pv64<<<dim3(6, 16, BDIM), 256, 0, stream>>>(S, cVFT, nullptr, out, rsp, bvf);
}

// Round 10
// 319.152 us; speedup vs baseline: 1.3053x; 1.3053x over previous
//
#include <hip/hip_runtime.h>
#include <math.h>

#define BDIM 8
#define MDIM 1024
#define CDIM 768
#define ROWS (BDIM * MDIM)   // 8192

typedef __attribute__((ext_vector_type(8))) short short8;   // 8 bf16
typedef __attribute__((ext_vector_type(8))) unsigned short ushort8;
typedef __attribute__((ext_vector_type(4))) float f32x4;

#define MFMA16(a, b, c) __builtin_amdgcn_mfma_f32_16x16x32_bf16((a), (b), (c), 0, 0, 0)

#define BAR() __builtin_amdgcn_s_barrier()
#define FENCE() asm volatile("" ::: "memory")
#define SCHED_FENCE() __builtin_amdgcn_sched_barrier(0)
#define WAIT_LGKM0() asm volatile("s_waitcnt lgkmcnt(0)" ::: "memory")
#define WAIT_LGKM4() asm volatile("s_waitcnt lgkmcnt(4)" ::: "memory")
#define WAIT_LGKM8() asm volatile("s_waitcnt lgkmcnt(8)" ::: "memory")
#define WAIT_VM8() asm volatile("s_waitcnt vmcnt(8)" ::: "memory")
#define WAIT_VM6() asm volatile("s_waitcnt vmcnt(6)" ::: "memory")
#define WAIT_VM4() asm volatile("s_waitcnt vmcnt(4)" ::: "memory")
#define WAIT_VM2() asm volatile("s_waitcnt vmcnt(2)" ::: "memory")
#define WAIT_VM0() asm volatile("s_waitcnt vmcnt(0)" ::: "memory")

__device__ __forceinline__ unsigned short f2bf(float f) {
  unsigned u = __float_as_uint(f);
  return (unsigned short)((u + 0x7FFFu + ((u >> 16) & 1u)) >> 16);
}

// Inline-asm ds_read_b128 (counted lgkm waits only bind to asm reads).
__device__ __forceinline__ short8 dsr128(unsigned off) {
  short8 r;
  asm volatile("ds_read_b128 %0, %1" : "=v"(r) : "v"(off));
  return r;
}

// ---------------------------------------------------------------------------
// Prologue: input converts + weight transpose-converts + V-slice row copies
// + folded biases. Flat grid of 10758 blocks x 256 threads:
//   [0,3072): convert layout_x; [3072,6144): convert text_x;
//   [6144,10176): transpose_w (168x24);
//   [10176,10464): Wqkv_vr[r][c] = bf16(Wqkv[r][1536+c])   (768x768)
//   [10464,10752): Wkv_vr[r][c]  = bf16(Wkv[r][768+c])     (768x768)
//   [10752,10758): bvq[n] = bqkv_v@Wq + bq; bvf[n] = bkv_v@Wffn + bffn
//     (6 blocks x 128 n x 2 outputs; unroll-16 c-loop, coalesced over n.
//      R9 bug: this lived in ONE wpre block with a NON-unrolled 768-iter
//      dependent-load loop -> ~450 cyc/iter -> 137 us kernel tail.)
// ---------------------------------------------------------------------------
__global__ __launch_bounds__(256) void prologue(
    const float* __restrict__ xl, const float* __restrict__ xt,
    unsigned short* __restrict__ dxl, unsigned short* __restrict__ dxt,
    const float* __restrict__ W0, const float* __restrict__ W1,
    const float* __restrict__ W2, const float* __restrict__ W3,
    unsigned short* __restrict__ D0, unsigned short* __restrict__ D1,
    unsigned short* __restrict__ D2, unsigned short* __restrict__ D3,
    unsigned short* __restrict__ VR0, unsigned short* __restrict__ VR1,
    const float* __restrict__ bqkv, const float* __restrict__ bq,
    const float* __restrict__ bkv, const float* __restrict__ bffn,
    float* __restrict__ bvq, float* __restrict__ bvf) {
  const int bx = blockIdx.x;
  const int tid = threadIdx.x;
  if (bx < 6144) {
    const float* src = bx < 3072 ? xl : xt;
    unsigned short* dst = bx < 3072 ? dxl : dxt;
    const int i = ((bx < 3072 ? bx : bx - 3072) * 256 + tid) * 8;
    const float4 a = *(const float4*)(src + i);
    const float4 b = *(const float4*)(src + i + 4);
    ushort8 o;
    o[0] = f2bf(a.x); o[1] = f2bf(a.y); o[2] = f2bf(a.z); o[3] = f2bf(a.w);
    o[4] = f2bf(b.x); o[5] = f2bf(b.y); o[6] = f2bf(b.z); o[7] = f2bf(b.w);
    *(ushort8*)(dst + i) = o;
  } else if (bx < 10176) {
    int x = bx - 6144;
    int bxx = x % 168;
    const int k0 = (x / 168) * 32;
    const float* W; unsigned short* D; int N;
    if (bxx < 72)       { W = W0; D = D0; N = 2304; }
    else if (bxx < 96)  { W = W1; D = D1; N = 768;  bxx -= 72; }
    else if (bxx < 144) { W = W2; D = D2; N = 1536; bxx -= 96; }
    else                { W = W3; D = D3; N = 768;  bxx -= 144; }
    __shared__ unsigned short t[32][33];
    const int tx = tid & 31, ty = tid >> 5;
    const int n0 = bxx * 32;
#pragma unroll
    for (int i = 0; i < 4; ++i)
      t[ty + i * 8][tx] = f2bf(W[(size_t)(k0 + ty + i * 8) * N + n0 + tx]);
    __syncthreads();
#pragma unroll
    for (int i = 0; i < 4; ++i)
      D[(size_t)(n0 + ty + i * 8) * CDIM + k0 + tx] = t[tx][ty + i * 8];
  } else if (bx < 10752) {
    const int isQ = bx < 10464;
    const int x = bx - (isQ ? 10176 : 10464);       // [0,288)
    const int i = (x * 256 + tid) * 8;               // < 589824; 768%8==0
    const int row = i / 768, col = i - row * 768;
    const float* src = isQ ? (W0 + (size_t)row * 2304 + 1536 + col)
                           : (W2 + (size_t)row * 1536 + 768 + col);
    unsigned short* dst = (isQ ? VR0 : VR1) + i;
    const float4 a = *(const float4*)(src);
    const float4 b = *(const float4*)(src + 4);
    ushort8 o;
    o[0] = f2bf(a.x); o[1] = f2bf(a.y); o[2] = f2bf(a.z); o[3] = f2bf(a.w);
    o[4] = f2bf(b.x); o[5] = f2bf(b.y); o[6] = f2bf(b.z); o[7] = f2bf(b.w);
    *(ushort8*)(dst) = o;
  } else {
    // folded biases: 6 blocks x (128 n x 2 matrices)
    const int blkb = bx - 10752;                     // 0..5
    const int n = blkb * 128 + (tid & 127);
    const int m = tid >> 7;                          // 0 -> bvq, 1 -> bvf
    const float* Wv = m ? W3 : W1;                   // Wffn : Wq (row-major 768x768)
    const float* bvec = m ? (bkv + 768) : (bqkv + 1536);
    float s = (m ? bffn : bq)[n];
#pragma unroll 16
    for (int c = 0; c < 768; ++c)
      s += bvec[c] * Wv[(size_t)c * 768 + n];
    (m ? bvf : bvq)[n] = s;
  }
}

// ---------------------------------------------------------------------------
// Shared staging: J row-groups of 8 rows x 64 cols per wave, XOR-chunked.
// ---------------------------------------------------------------------------
template <int J>
__device__ __forceinline__ void stageJ(
    const unsigned short* __restrict__ g, int ld, int k0,
    unsigned short* lds, int wave, int lane) {
  const int gchunk = (lane & 7) ^ (lane >> 3);
#pragma unroll
  for (int j = 0; j < J; ++j) {
    const int grp = wave * J + j;
    const unsigned short* gp =
        g + (size_t)(grp * 8 + (lane >> 3)) * ld + k0 + gchunk * 8;
    __builtin_amdgcn_global_load_lds(
        (const __attribute__((address_space(1))) unsigned int*)gp,
        (__attribute__((address_space(3))) unsigned int*)(lds + grp * 512),
        16, 0, 0);
  }
}

// ---------------------------------------------------------------------------
// 64x128-tile MFMA engine (4 waves of 32x64, acc[2][4]).
// ---------------------------------------------------------------------------
__device__ __forceinline__ void mfma_loop64h(
    const unsigned short* __restrict__ A, int lda,
    const unsigned short* __restrict__ Bt, int ldb, int K,
    unsigned short* As, unsigned short* Bs, f32x4 acc[2][4],
    int wave, int lane) {
  const int wx = wave & 1, wy = wave >> 1;
  const int quad = lane >> 4, l16 = lane & 15;
  for (int k0 = 0; k0 < K; k0 += 64) {
    stageJ<2>(A, lda, k0, As, wave, lane);
    stageJ<4>(Bt, ldb, k0, Bs, wave, lane);
    __syncthreads();
#pragma unroll
    for (int h = 0; h < 2; ++h) {
      const int slot = ((((h << 2) | quad) ^ (l16 & 7))) * 8;
      short8 afr[2], bfr[4];
#pragma unroll
      for (int mt = 0; mt < 2; ++mt)
        afr[mt] = *(const short8*)&As[(wy * 32 + mt * 16 + l16) * 64 + slot];
#pragma unroll
      for (int nt = 0; nt < 4; ++nt)
        bfr[nt] = *(const short8*)&Bs[(wx * 64 + nt * 16 + l16) * 64 + slot];
#pragma unroll
      for (int mt = 0; mt < 2; ++mt)
#pragma unroll
        for (int nt = 0; nt < 4; ++nt)
          acc[mt][nt] = MFMA16(afr[mt], bfr[nt], acc[mt][nt]);
    }
    __syncthreads();
  }
}

// ---------------------------------------------------------------------------
// wpre: folded projection weights, pure GEMM. Flat grid 144.
//   blocks [0,72):   Wvq_t[n][c] = (Wqkv_v @ Wq)^T  (12 m-tiles x 6 c-tiles)
//   blocks [72,144): Wvf_t[d][c] = (Wkv_v @ Wffn)^T
// ---------------------------------------------------------------------------
__global__ __launch_bounds__(256, 4) void wpre(
    const unsigned short* __restrict__ Wq_t, const unsigned short* __restrict__ VR0,
    const unsigned short* __restrict__ Wffn_t, const unsigned short* __restrict__ VR1,
    unsigned short* __restrict__ Wvq_t, unsigned short* __restrict__ Wvf_t) {
  __shared__ __align__(16) unsigned short As[64 * 64];
  __shared__ __align__(16) unsigned short Bs[128 * 64];
  const int tid = threadIdx.x;
  int g = blockIdx.x;
  const unsigned short *A, *Bt; unsigned short* D;
  if (g < 72) { A = Wq_t; Bt = VR0; D = Wvq_t; }
  else { g -= 72; A = Wffn_t; Bt = VR1; D = Wvf_t; }
  const int m0 = (g % 12) * 64, c0 = (g / 12) * 128;   // 12 x 6 tiles
  const int wave = tid >> 6, lane = tid & 63;
  const int wx = wave & 1, wy = wave >> 1;
  const int quad = lane >> 4, l16 = lane & 15;
  const f32x4 vzero = {0.f, 0.f, 0.f, 0.f};
  f32x4 acc[2][4];
#pragma unroll
  for (int mt = 0; mt < 2; ++mt)
#pragma unroll
    for (int nt = 0; nt < 4; ++nt) acc[mt][nt] = vzero;
  mfma_loop64h(A + (size_t)m0 * CDIM, CDIM, Bt + (size_t)c0 * CDIM, CDIM,
               CDIM, As, Bs, acc, wave, lane);
#pragma unroll
  for (int mt = 0; mt < 2; ++mt)
#pragma unroll
    for (int nt = 0; nt < 4; ++nt) {
      const int col = c0 + wx * 64 + nt * 16 + l16;
#pragma unroll
      for (int rg = 0; rg < 4; ++rg) {
        const int row = m0 + wy * 32 + mt * 16 + quad * 4 + rg;
        D[(size_t)row * 768 + col] = f2bf(acc[mt][nt][rg]);
      }
    }
}

#define MFMA_PHASE(GM, GN, AA, BB)                                          \
  do {                                                                      \
    SCHED_FENCE();                                                          \
    __builtin_amdgcn_s_setprio(1);                                          \
    _Pragma("unroll") for (int mf = 0; mf < 4; ++mf)                        \
    _Pragma("unroll") for (int nf = 0; nf < 2; ++nf)                        \
    _Pragma("unroll") for (int kh = 0; kh < 2; ++kh)                        \
        acc[GM][GN][mf][nf] =                                               \
            MFMA16(AA[mf][kh], BB[nf][kh], acc[GM][GN][mf][nf]);            \
    __builtin_amdgcn_s_setprio(0);                                          \
    SCHED_FENCE();                                                          \
  } while (0)

#define RD_A(dst, base)                                                     \
  do {                                                                      \
    _Pragma("unroll") for (int mf = 0; mf < 4; ++mf) {                      \
      dst[mf][0] = dsr128((base) + aRow[mf] + sl0);                         \
      dst[mf][1] = dsr128((base) + aRow[mf] + sl1);                         \
    }                                                                       \
  } while (0)
#define RD_B(dst, base)                                                     \
  do {                                                                      \
    _Pragma("unroll") for (int nf = 0; nf < 2; ++nf) {                      \
      dst[nf][0] = dsr128((base) + bRow[nf] + sl0);                         \
      dst[nf][1] = dsr128((base) + bRow[nf] + sl1);                         \
    }                                                                       \
  } while (0)

// ---------------------------------------------------------------------------
// 256x256 engine (R7 asm-ds_read pipelined schedule, bench 62 us).
// The LAST 768-slice of each part uses the FOLDED weight (Bvw: Wvq_t/Wvf_t)
// and is written transposed into vTd with ZERO bias (bias folded into the
// pv-stage's bvq/bvf).
// ---------------------------------------------------------------------------
__global__ __launch_bounds__(512, 2) void gemm_qkvkv(
    const unsigned short* __restrict__ A0g, const unsigned short* __restrict__ B0g,
    const float* __restrict__ bias0, unsigned short* __restrict__ Y0,
    unsigned short* __restrict__ vT0, const unsigned short* __restrict__ Bvw0,
    const unsigned short* __restrict__ A1g, const unsigned short* __restrict__ B1g,
    const float* __restrict__ bias1, unsigned short* __restrict__ Y1,
    unsigned short* __restrict__ vT1, const unsigned short* __restrict__ Bvw1) {
  __shared__ __align__(16) unsigned short lds[65536];  // 128 KiB, LDS addr 0
  int lin = blockIdx.x;
  const unsigned short *A, *Bt, *Balt; const float* bias;
  unsigned short *Y, *vTd; int lastSlice, m0, c0;
  if (lin < 288) {            // qkv: 32 m-tiles x 9 c-tiles
    A = A0g; Bt = B0g; Balt = Bvw0; bias = bias0; Y = Y0; vTd = vT0;
    lastSlice = 2;
    const int xcd = lin & 7, j = lin >> 3;          // j in [0,36)
    m0 = (xcd * 4 + (j & 3)) * 256; c0 = (j >> 2) * 256;
  } else {                    // kv: 32 m-tiles x 6 c-tiles
    lin -= 288;
    A = A1g; Bt = B1g; Balt = Bvw1; bias = bias1; Y = Y1; vTd = vT1;
    lastSlice = 1;
    const int xcd = lin & 7, j = lin >> 3;          // j in [0,24)
    m0 = (xcd * 4 + (j & 3)) * 256; c0 = (j >> 2) * 256;
  }
  // Folded-weight slice: swap B source (256-tiles never straddle 768-slices).
  const int sw = lastSlice * 768;
  const unsigned short* Bsel = Bt;
  int c0b = c0;
  if (c0 >= sw) { Bsel = Balt; c0b = c0 - sw; }

  const int tid = threadIdx.x;
  const int wave = tid >> 6, lane = tid & 63;
  const int wy = wave >> 2, wx = wave & 3;          // 2 x 4 waves
  const int quad = lane >> 4, l16 = lane & 15;

  const unsigned short* Ah[2] = {A + (size_t)m0 * CDIM,
                                 A + (size_t)(m0 + 128) * CDIM};
  const unsigned short* Bh[2] = {Bsel + (size_t)c0b * CDIM,
                                 Bsel + (size_t)(c0b + 128) * CDIM};

  const unsigned sl0 = (unsigned)((quad ^ (l16 & 7)) * 16);
  const unsigned sl1 = (unsigned)(((4 | quad) ^ (l16 & 7)) * 16);
  unsigned aRow[4], bRow[2];
#pragma unroll
  for (int mf = 0; mf < 4; ++mf)
    aRow[mf] = (unsigned)((wy * 64 + mf * 16 + l16) * 128);
#pragma unroll
  for (int nf = 0; nf < 2; ++nf)
    bRow[nf] = (unsigned)((wx * 32 + nf * 16 + l16) * 128);

  const f32x4 vzero = {0.f, 0.f, 0.f, 0.f};
  f32x4 acc[2][2][4][2];
#pragma unroll
  for (int gm = 0; gm < 2; ++gm)
#pragma unroll
    for (int gn = 0; gn < 2; ++gn)
#pragma unroll
      for (int mf = 0; mf < 4; ++mf)
#pragma unroll
        for (int nf = 0; nf < 2; ++nf) acc[gm][gn][mf][nf] = vzero;
  short8 afrE[4][2], afrO[4][2], b0r[2][2], b1r[2][2];

  stageJ<2>(Ah[0], CDIM, 0, lds + 0, wave, lane);
  stageJ<2>(Bh[0], CDIM, 0, lds + 16384, wave, lane);
  stageJ<2>(Bh[1], CDIM, 0, lds + 24576, wave, lane);
  stageJ<2>(Ah[1], CDIM, 0, lds + 8192, wave, lane);
  stageJ<2>(Ah[0], CDIM, 64, lds + 32768 + 0, wave, lane);
  stageJ<2>(Bh[0], CDIM, 64, lds + 32768 + 16384, wave, lane);
  stageJ<2>(Bh[1], CDIM, 64, lds + 32768 + 24576, wave, lane);
  WAIT_VM8();
  BAR(); FENCE();
  RD_A(afrE, 0u);        // A0(0) @ buf0
  RD_B(b0r, 32768u);     // B0(0) @ buf0

  for (int t = 0; t < 10; ++t) {
    unsigned short* bufcP = lds + (t & 1) * 32768;
    unsigned short* bufnP = lds + ((t + 1) & 1) * 32768;
    const unsigned bc = (unsigned)((t & 1) * 65536);
    const unsigned bn = (unsigned)(((t + 1) & 1) * 65536);
    // ---- P0 ----
    RD_B(b1r, bc + 49152u);
    stageJ<2>(Ah[1], CDIM, (t + 1) * 64, bufnP + 8192, wave, lane);
    WAIT_VM8(); BAR(); WAIT_LGKM4();
    MFMA_PHASE(0, 0, afrE, b0r);
    // ---- P1 ----
    RD_A(afrO, bc + 16384u);
    stageJ<2>(Ah[0], CDIM, (t + 2) * 64, bufcP + 0, wave, lane);
    WAIT_VM8(); BAR(); WAIT_LGKM8();
    MFMA_PHASE(0, 1, afrE, b1r);
    // ---- P2 ----
    RD_A(afrE, bn + 0u);
    stageJ<2>(Bh[0], CDIM, (t + 2) * 64, bufcP + 16384, wave, lane);
    WAIT_VM8(); BAR(); WAIT_LGKM8();
    MFMA_PHASE(1, 0, afrO, b0r);
    // ---- P3 ----
    RD_B(b0r, bn + 32768u);
    stageJ<2>(Bh[1], CDIM, (t + 2) * 64, bufcP + 24576, wave, lane);
    WAIT_VM8(); BAR();
    MFMA_PHASE(1, 1, afrO, b1r);
  }
  // ---- t = 10 ----
  {
    const unsigned bc = 0u, bn = 65536u;
    unsigned short* bufnP = lds + 32768;
    RD_B(b1r, bc + 49152u);
    stageJ<2>(Ah[1], CDIM, 11 * 64, bufnP + 8192, wave, lane);
    WAIT_VM8(); BAR(); WAIT_LGKM4();
    MFMA_PHASE(0, 0, afrE, b0r);

    RD_A(afrO, bc + 16384u);
    WAIT_VM6(); BAR(); WAIT_LGKM8();
    MFMA_PHASE(0, 1, afrE, b1r);

    RD_A(afrE, bn + 0u);
    WAIT_VM4(); BAR(); WAIT_LGKM8();
    MFMA_PHASE(1, 0, afrO, b0r);

    RD_B(b0r, bn + 32768u);
    WAIT_VM2(); BAR();
    MFMA_PHASE(1, 1, afrO, b1r);
  }
  // ---- t = 11 ----
  {
    const unsigned bc = 65536u;
    RD_B(b1r, bc + 49152u);
    WAIT_VM0(); BAR(); WAIT_LGKM4();
    MFMA_PHASE(0, 0, afrE, b0r);

    RD_A(afrO, bc + 16384u);
    WAIT_LGKM8();
    MFMA_PHASE(0, 1, afrE, b1r);

    WAIT_LGKM0();
    MFMA_PHASE(1, 0, afrO, b0r);
    MFMA_PHASE(1, 1, afrO, b1r);
  }

  // Epilogue: slice-routed writes; last slice transposed (folded weight,
  // bias = 0: it is added post-normalize in the pv stage).
#pragma unroll
  for (int gm = 0; gm < 2; ++gm)
#pragma unroll
    for (int gn = 0; gn < 2; ++gn) {
      const int cb2 = c0 + gn * 128 + wx * 32;
      const int slice = cb2 / 768;
      const int rb = m0 + gm * 128 + wy * 64;
      if (slice == lastSlice) {
#pragma unroll
        for (int mf = 0; mf < 4; ++mf) {
          const int row0 = rb + mf * 16 + quad * 4;
          const int b = row0 >> 10, n0 = row0 & 1023;
#pragma unroll
          for (int nf = 0; nf < 2; ++nf) {
            const int gcol = cb2 + nf * 16 + l16;
            const int d = gcol - slice * 768;
            uint2 o;
            o.x = (unsigned)f2bf(acc[gm][gn][mf][nf][0]) |
                  ((unsigned)f2bf(acc[gm][gn][mf][nf][1]) << 16);
            o.y = (unsigned)f2bf(acc[gm][gn][mf][nf][2]) |
                  ((unsigned)f2bf(acc[gm][gn][mf][nf][3]) << 16);
            *(uint2*)&vTd[((size_t)b * CDIM + d) * MDIM + n0] = o;
          }
        }
      } else {
        const size_t sbase = (size_t)slice * ROWS * 768;
#pragma unroll
        for (int mf = 0; mf < 4; ++mf)
#pragma unroll
          for (int nf = 0; nf < 2; ++nf) {
            const int gcol = cb2 + nf * 16 + l16;
            const int lcol = gcol - slice * 768;
            const float bv = bias[gcol];
#pragma unroll
            for (int rg = 0; rg < 4; ++rg) {
              const int row = rb + mf * 16 + quad * 4 + rg;
              Y[sbase + (size_t)row * 768 + lcol] =
                  f2bf(acc[gm][gn][mf][nf][rg] + bv);
            }
          }
      }
    }
}

// ---------------------------------------------------------------------------
// Batched QK^T with fused exp + row-sum on the 64x128 engine.
// grid (8, 16, BDIM) = 1024 blocks. Row sums as race-free partials per
// (cblock, wx): rsp[((cb*2+wx)*8 + b)*1024 + row].
// ---------------------------------------------------------------------------
__global__ __launch_bounds__(256, 4) void gemm_qk64(
    const unsigned short* __restrict__ Qb, const unsigned short* __restrict__ Kb,
    const float* __restrict__ mask, unsigned short* __restrict__ S, float scale,
    float* __restrict__ rsp) {
  __shared__ __align__(16) unsigned short As[64 * 64];
  __shared__ __align__(16) unsigned short Bs[128 * 64];
  const int c0 = blockIdx.x * 128;
  const int m0 = blockIdx.y * 64;
  const int b = blockIdx.z;
  const int tid = threadIdx.x;
  const int wave = tid >> 6, lane = tid & 63;
  const int wx = wave & 1, wy = wave >> 1;
  const int quad = lane >> 4, l16 = lane & 15;

  const f32x4 vzero = {0.f, 0.f, 0.f, 0.f};
  f32x4 acc[2][4];
#pragma unroll
  for (int mt = 0; mt < 2; ++mt)
#pragma unroll
    for (int nt = 0; nt < 4; ++nt) acc[mt][nt] = vzero;

  mfma_loop64h(Qb + ((size_t)b * MDIM + m0) * CDIM, CDIM,
               Kb + ((size_t)b * MDIM + c0) * CDIM, CDIM, CDIM,
               As, Bs, acc, wave, lane);

  const float* maskb = mask + b * MDIM;
  float mrow[2][4], rsum[2][4];
#pragma unroll
  for (int mt = 0; mt < 2; ++mt)
#pragma unroll
    for (int rg = 0; rg < 4; ++rg) {
      mrow[mt][rg] = maskb[m0 + wy * 32 + mt * 16 + quad * 4 + rg];
      rsum[mt][rg] = 0.f;
    }
  unsigned short* Sb = S + (size_t)b * MDIM * MDIM;
#pragma unroll
  for (int nt = 0; nt < 4; ++nt) {
    const int col = c0 + wx * 64 + nt * 16 + l16;
    const float mcol = maskb[col];
#pragma unroll
    for (int mt = 0; mt < 2; ++mt)
#pragma unroll
      for (int rg = 0; rg < 4; ++rg) {
        const int row = m0 + wy * 32 + mt * 16 + quad * 4 + rg;
        const float e = (mrow[mt][rg] * mcol != 0.f)
                            ? __expf(acc[mt][nt][rg] * scale)
                            : 1e-30f;
        Sb[(size_t)row * MDIM + col] = f2bf(e);
        rsum[mt][rg] += e;
      }
  }
  for (int off = 1; off < 16; off <<= 1) {
#pragma unroll
    for (int mt = 0; mt < 2; ++mt)
#pragma unroll
      for (int rg = 0; rg < 4; ++rg)
        rsum[mt][rg] += __shfl_xor(rsum[mt][rg], off, 64);
  }
  if (l16 == 0) {
    float* rs = rsp + ((((size_t)blockIdx.x * 2 + wx) * 8 + b) << 10) +
                m0 + wy * 32;
#pragma unroll
    for (int mt = 0; mt < 2; ++mt)
#pragma unroll
      for (int rg = 0; rg < 4; ++rg)
        rs[mt * 16 + quad * 4 + rg] = rsum[mt][rg];
  }
}

// ---------------------------------------------------------------------------
// O = normalize(S) @ B + bias  on the 64x128 engine; B is a vT-format
// [b][d][n] operand. Writes bf16 (Ob) or f32 (Of) — exactly one non-null.
// Bias is added AFTER normalization (exact fold: normalized rows sum to 1).
// grid (6, 16, BDIM) = 768 blocks.
// ---------------------------------------------------------------------------
__global__ __launch_bounds__(256, 4) void attn_pv64(
    const unsigned short* __restrict__ P, const unsigned short* __restrict__ vT,
    unsigned short* __restrict__ Ob, float* __restrict__ Of,
    const float* __restrict__ rsp, const float* __restrict__ bias) {
  __shared__ __align__(16) unsigned short As[64 * 64];
  __shared__ __align__(16) unsigned short Bs[128 * 64];
  const int c0 = blockIdx.x * 128;
  const int m0 = blockIdx.y * 64;
  const int b = blockIdx.z;
  const int tid = threadIdx.x;
  const int wave = tid >> 6, lane = tid & 63;
  const int wx = wave & 1, wy = wave >> 1;
  const int quad = lane >> 4, l16 = lane & 15;

  const f32x4 vzero = {0.f, 0.f, 0.f, 0.f};
  f32x4 acc[2][4];
#pragma unroll
  for (int mt = 0; mt < 2; ++mt)
#pragma unroll
    for (int nt = 0; nt < 4; ++nt) acc[mt][nt] = vzero;

  mfma_loop64h(P + ((size_t)b * MDIM + m0) * MDIM, MDIM,
               vT + ((size_t)b * CDIM + c0) * MDIM, MDIM, MDIM,
               As, Bs, acc, wave, lane);

  const float* rsb = rsp + (((size_t)l16 * 8 + b) << 10) + m0 + wy * 32;
  float inv[2][4];
#pragma unroll
  for (int mt = 0; mt < 2; ++mt)
#pragma unroll
    for (int rg = 0; rg < 4; ++rg) {
      float s = rsb[mt * 16 + quad * 4 + rg];
      for (int off = 1; off < 16; off <<= 1) s += __shfl_xor(s, off, 64);
      inv[mt][rg] = 1.f / s;
    }
#pragma unroll
  for (int mt = 0; mt < 2; ++mt)
#pragma unroll
    for (int nt = 0; nt < 4; ++nt) {
      const int col = c0 + wx * 64 + nt * 16 + l16;
      const float bv = bias[col];
#pragma unroll
      for (int rg = 0; rg < 4; ++rg) {
        const int row = m0 + wy * 32 + mt * 16 + quad * 4 + rg;
        const float v = acc[mt][nt][rg] * inv[mt][rg] + bv;
        if (Of) Of[(size_t)(b * MDIM + row) * CDIM + col] = v;
        else Ob[(size_t)(b * MDIM + row) * CDIM + col] = f2bf(v);
      }
    }
}

// ---------------------------------------------------------------------------
extern "C" void kernel_launch(void* const* d_in, const int* in_sizes, int n_in,
                              void* d_out, int out_size, void* d_ws, size_t ws_size,
                              hipStream_t stream) {
  const float* layout_x = (const float*)d_in[0];
  const float* text_x   = (const float*)d_in[1];
  const float* maskp    = (const float*)d_in[2];
  const float* Wqkv     = (const float*)d_in[3];
  const float* bqkv     = (const float*)d_in[4];
  const float* Wq       = (const float*)d_in[5];
  const float* bq       = (const float*)d_in[6];
  const float* Wkv      = (const float*)d_in[7];
  const float* bkv      = (const float*)d_in[8];
  const float* Wffn     = (const float*)d_in[9];
  const float* bffn     = (const float*)d_in[10];
  float* out = (float*)d_out;
  char* ws = (char*)d_ws;

  const float scale = 1.0f / sqrtf((float)CDIM);

  // ---- workspace (bytes), end 117,839,872 ----
  unsigned short* xlb     = (unsigned short*)(ws);              // dead after qkvkv
  unsigned short* xtb     = (unsigned short*)(ws + 12582912);   // -> rsp
  unsigned short* Wqkv_t  = (unsigned short*)(ws + 25165824);
  unsigned short* Wq_t    = (unsigned short*)(ws + 28704768);
  unsigned short* Wkv_t   = (unsigned short*)(ws + 29884416);
  unsigned short* Wffn_t  = (unsigned short*)(ws + 32243712);
  unsigned short* Wvq_t   = (unsigned short*)(ws + 33423360);   // folded V@Wq ^T
  unsigned short* Wvf_t   = (unsigned short*)(ws + 34603008);   // folded cV@Wffn ^T
  unsigned short* Qb      = (unsigned short*)(ws + 35782656);   // cqb alias after qk1
  unsigned short* Kb      = (unsigned short*)(ws + 48365568);   // = Qb + 12,582,912
  unsigned short* VWT     = (unsigned short*)(ws + 60948480);   // (x@Wvq)^T [b][d][n]
  unsigned short* cK      = (unsigned short*)(ws + 73531392);
  unsigned short* cVFT    = (unsigned short*)(ws + 86114304);   // (text@Wvf)^T
  unsigned short* S       = (unsigned short*)(ws + 98697216);   // 16.8 MB
  float*          bvq     = (float*)(ws + 115474432);           // 3 KB
  float*          bvf     = (float*)(ws + 115477504);           // 3 KB
  unsigned short* Wqkv_vr = (unsigned short*)(ws + 115480576);  // 1.18 MB
  unsigned short* Wkv_vr  = (unsigned short*)(ws + 116660224);  // 1.18 MB
  unsigned short* cqb     = Qb;          // Qb dead after qk1
  float* rsp = (float*)xtb;              // xtb dead after qkvkv

  // 1) prologue: converts + weight transposes + V-slice copies + folded biases
  prologue<<<10758, 256, 0, stream>>>(layout_x, text_x, xlb, xtb,
                                      Wqkv, Wq, Wkv, Wffn,
                                      Wqkv_t, Wq_t, Wkv_t, Wffn_t,
                                      Wqkv_vr, Wkv_vr,
                                      bqkv, bq, bkv, bffn, bvq, bvf);
  // 2) folded projection weights Wvq_t, Wvf_t (pure GEMM, 144 blocks)
  wpre<<<144, 256, 0, stream>>>(Wq_t, Wqkv_vr, Wffn_t, Wkv_vr, Wvq_t, Wvf_t);
  // 3) combined 256^2: {Q,K -> Qb,Kb; x@Wvq -> VWT^T} + {cK; text@Wvf -> cVFT^T}
  gemm_qkvkv<<<480, 512, 0, stream>>>(xlb, Wqkv_t, bqkv, Qb, VWT, Wvq_t,
                                      xtb, Wkv_t, bkv, cK, cVFT, Wvf_t);
  // 4) S = exp(scale*QK^T) masked; rowsum partials
  gemm_qk64<<<dim3(8, 16, BDIM), 256, 0, stream>>>(Qb, Kb, maskp, S, scale, rsp);
  // 5) cq = normalize(S) @ VW + bvq   (pv + folded Wq projection)
  attn_pv64<<<dim3(6, 16, BDIM), 256, 0, stream>>>(S, VWT, cqb, nullptr, rsp, bvq);
  // 6) S = exp(scale*cq cK^T) masked; rowsum partials
  gemm_qk64<<<dim3(8, 16, BDIM), 256, 0, stream>>>(cqb, cK, maskp, S, scale, rsp);
  // 7) out = normalize(S) @ cVF + bvf   (pv + folded Wffn projection, f32)
  attn_pv64<<<dim3(6, 16, BDIM), 256, 0, stream>>>(S, cVFT, nullptr, out, rsp, bvf);
}